// Round 1
// baseline (247.777 us; speedup 1.0000x reference)
//
#include <hip/hip_runtime.h>
#include <hip/hip_bf16.h>

#define N_NODES 12000
#define N_EDGES 384000
#define F_IN 512
#define H 64
#define C_CLS 7
#define KTERMS 24

// ---------------------------------------------------------------- utilities
__device__ __forceinline__ float wred_f(float x) {
    #pragma unroll
    for (int o = 32; o > 0; o >>= 1) x += __shfl_xor(x, o);
    return x;
}
__device__ __forceinline__ double wred_d(double x) {
    #pragma unroll
    for (int o = 32; o > 0; o >>= 1) x += __shfl_xor(x, o);
    return x;
}

// ---------------------------------------------------------------- deg init / count / invs
__global__ void init_deg_k(float* __restrict__ deg) {
    int i = blockIdx.x * 256 + threadIdx.x;
    if (i < N_NODES) deg[i] = 1.0f;   // self-loop
}

__global__ void count_k(const int* __restrict__ ei, float* __restrict__ deg) {
    int e = blockIdx.x * 256 + threadIdx.x;
    if (e < N_EDGES) {
        int d = ei[N_EDGES + e];
        unsafeAtomicAdd(&deg[d], 1.0f);
    }
}

__global__ void invs_k(const float* __restrict__ deg, float* __restrict__ invs) {
    int i = blockIdx.x * 256 + threadIdx.x;
    if (i < N_NODES) invs[i] = 1.0f / sqrtf(deg[i]);
}

// ---------------------------------------------------------------- exclusive scan of in-degree -> CSR ptr
__global__ void scan_k(const float* __restrict__ deg, int* __restrict__ ptr) {
    __shared__ int sums[256];
    int t = threadIdx.x;
    const int CH = 47;                 // 256*47 = 12032 >= 12000
    int base = t * CH;
    int s = 0;
    for (int q = 0; q < CH; ++q) {
        int idx = base + q;
        if (idx < N_NODES) s += (int)deg[idx] - 1;
    }
    sums[t] = s;
    __syncthreads();
    // Hillis-Steele inclusive scan
    for (int o = 1; o < 256; o <<= 1) {
        int v = (t >= o) ? sums[t - o] : 0;
        __syncthreads();
        sums[t] += v;
        __syncthreads();
    }
    int run = sums[t] - s;             // exclusive prefix for this chunk
    for (int q = 0; q < CH; ++q) {
        int idx = base + q;
        if (idx < N_NODES) {
            ptr[idx] = run;
            run += (int)deg[idx] - 1;
        }
    }
    if (t == 255) ptr[N_NODES] = sums[255];
}

__global__ void fill_k(const int* __restrict__ ei, const int* __restrict__ ptr,
                       int* __restrict__ cur, int* __restrict__ csrc) {
    int e = blockIdx.x * 256 + threadIdx.x;
    if (e < N_EDGES) {
        int s = ei[e];
        int d = ei[N_EDGES + e];
        int pos = atomicAdd(&cur[d], 1);
        csrc[ptr[d] + pos] = s;
    }
}

// ---------------------------------------------------------------- gemm1: h = x @ W1   [12000x512]@[512x64]
__global__ __launch_bounds__(256) void gemm1_k(const float* __restrict__ x,
                                               const float* __restrict__ W1,
                                               float* __restrict__ outh) {
    __shared__ float xsT[64][34];      // [kk][m], padded
    __shared__ float wsm[64][64];      // [kk][f]
    int t = threadIdx.x;
    int tx = t & 15, ty = t >> 4;      // tx: col group (4 cols), ty: row pair (2 rows)
    int i0 = blockIdx.x * 32;
    float acc[2][4] = {};
    for (int k0 = 0; k0 < F_IN; k0 += 64) {
        for (int idx = t; idx < 512; idx += 256) {       // x tile 32x64
            int m = idx >> 4, c4 = idx & 15;
            float4 v = *(const float4*)(x + (size_t)(i0 + m) * F_IN + k0 + c4 * 4);
            xsT[c4 * 4 + 0][m] = v.x;
            xsT[c4 * 4 + 1][m] = v.y;
            xsT[c4 * 4 + 2][m] = v.z;
            xsT[c4 * 4 + 3][m] = v.w;
        }
        for (int idx = t; idx < 1024; idx += 256) {      // W1 tile 64x64
            int r = idx >> 4, c4 = idx & 15;
            *(float4*)(&wsm[r][c4 * 4]) = *(const float4*)(W1 + (size_t)(k0 + r) * H + c4 * 4);
        }
        __syncthreads();
        #pragma unroll
        for (int kk = 0; kk < 64; ++kk) {
            float2 a = *(const float2*)(&xsT[kk][ty * 2]);
            float4 b = *(const float4*)(&wsm[kk][tx * 4]);
            acc[0][0] += a.x * b.x; acc[0][1] += a.x * b.y;
            acc[0][2] += a.x * b.z; acc[0][3] += a.x * b.w;
            acc[1][0] += a.y * b.x; acc[1][1] += a.y * b.y;
            acc[1][2] += a.y * b.z; acc[1][3] += a.y * b.w;
        }
        __syncthreads();
    }
    #pragma unroll
    for (int q = 0; q < 2; ++q) {
        float4 v = make_float4(acc[q][0], acc[q][1], acc[q][2], acc[q][3]);
        *(float4*)(outh + (size_t)(i0 + ty * 2 + q) * H + tx * 4) = v;
    }
}

// ---------------------------------------------------------------- gemm2: t = h1 @ W2   [12000x64]@[64x64]
__global__ __launch_bounds__(256) void gemm2_k(const float* __restrict__ hin,
                                               const float* __restrict__ W2,
                                               float* __restrict__ outh) {
    __shared__ float ws2[64][64];
    __shared__ float hs[32][64];
    int t = threadIdx.x;
    int i0 = blockIdx.x * 32;
    for (int idx = t; idx < 1024; idx += 256) {
        int r = idx >> 4, c4 = idx & 15;
        *(float4*)(&ws2[r][c4 * 4]) = *(const float4*)(W2 + (size_t)r * H + c4 * 4);
    }
    for (int idx = t; idx < 512; idx += 256) {
        int m = idx >> 4, c4 = idx & 15;
        *(float4*)(&hs[m][c4 * 4]) = *(const float4*)(hin + (size_t)(i0 + m) * H + c4 * 4);
    }
    __syncthreads();
    int f = t & 63, g = t >> 6;
    #pragma unroll
    for (int m = 0; m < 8; ++m) {
        int row = m * 4 + g;
        float acc = 0.f;
        #pragma unroll 16
        for (int k = 0; k < 64; ++k) acc += hs[row][k] * ws2[k][f];
        outh[(size_t)(i0 + row) * H + f] = acc;
    }
}

// ---------------------------------------------------------------- GCN aggregate (CSR gather), optional relu
__global__ void agg_k(const float* __restrict__ hin, const float* __restrict__ bias,
                      const float* __restrict__ deg, const float* __restrict__ invs,
                      const int* __restrict__ ptr, const int* __restrict__ csrc,
                      float* __restrict__ out, int relu) {
    int i = blockIdx.x;
    int f = threadIdx.x;
    float isd = invs[i];
    float acc = hin[(size_t)i * H + f] / deg[i] + bias[f];
    int p0 = ptr[i], p1 = ptr[i + 1];
    for (int p = p0; p < p1; ++p) {
        int s = csrc[p];
        acc += hin[(size_t)s * H + f] * (invs[s] * isd);
    }
    if (relu) acc = fmaxf(acc, 0.f);
    out[(size_t)i * H + f] = acc;
}

// ---------------------------------------------------------------- score_i = (h2_i . a)/max(||h2_i||,1e-8)
__global__ void score_k(const float* __restrict__ h2, const float* __restrict__ aux,
                        float* __restrict__ score) {
    int t = threadIdx.x;
    int wave = t >> 6, lane = t & 63;
    int i = blockIdx.x * 4 + wave;
    float av = aux[lane];
    float na = wred_f(av * av);
    float an = av / fmaxf(sqrtf(na), 1e-12f);
    float v = h2[(size_t)i * H + lane];
    float hd = wred_f(v * an);
    float hn = wred_f(v * v);
    if (lane == 0) score[i] = hd / fmaxf(sqrtf(hn), 1e-8f);
}

// ---------------------------------------------------------------- moments: M[k][f] = sum_j e^{-sj^2} sj^k h2[j][f]
__global__ __launch_bounds__(256) void moments_k(const float* __restrict__ h2,
                                                 const float* __restrict__ score,
                                                 double* __restrict__ M) {
    int t = threadIdx.x;
    int f = t & 63, g = t >> 6;
    double acc[KTERMS];
    #pragma unroll
    for (int k = 0; k < KTERMS; ++k) acc[k] = 0.0;
    for (int j = blockIdx.x * 4 + g; j < N_NODES; j += 256) {
        float sj = score[j];
        double sd = (double)sj;
        double w = exp(-sd * sd);
        double tt = w * (double)h2[(size_t)j * H + f];
        #pragma unroll
        for (int k = 0; k < KTERMS; ++k) { acc[k] += tt; tt *= sd; }
    }
    __shared__ double red[256];
    #pragma unroll
    for (int k = 0; k < KTERMS; ++k) {
        red[t] = acc[k];
        __syncthreads();
        if (t < 64)
            unsafeAtomicAdd(&M[k * 64 + t], red[t] + red[t + 64] + red[t + 128] + red[t + 192]);
        __syncthreads();
    }
}

// ---------------------------------------------------------------- denominator moments m0[k] = sum_j e^{-sj^2} sj^k
__global__ void den_k(const float* __restrict__ score, double* __restrict__ m0) {
    int j = blockIdx.x * 64 + threadIdx.x;
    double t = 0.0, sd = 0.0;
    if (j < N_NODES) {
        float s = score[j];
        sd = (double)s;
        t = exp(-sd * sd);
    }
    #pragma unroll
    for (int k = 0; k < KTERMS; ++k) {
        double r = wred_d(t);
        if (threadIdx.x == 0) unsafeAtomicAdd(&m0[k], r);
        t *= sd;
    }
}

// ---------------------------------------------------------------- final: z + concat-classifier
__global__ __launch_bounds__(256) void final_k(const float* __restrict__ h2,
                                               const float* __restrict__ score,
                                               const double* __restrict__ M,
                                               const double* __restrict__ m0,
                                               const float* __restrict__ clfW,
                                               const float* __restrict__ clfb,
                                               float* __restrict__ out) {
    __shared__ double Ms[KTERMS * 64];
    __shared__ double m0s[KTERMS];
    __shared__ float cw[128 * C_CLS];
    __shared__ float cb[8];
    __shared__ float zh[4][128];
    int t = threadIdx.x;
    for (int idx = t; idx < KTERMS * 64; idx += 256) Ms[idx] = M[idx];
    if (t < KTERMS) m0s[t] = m0[t];
    for (int idx = t; idx < 128 * C_CLS; idx += 256) cw[idx] = clfW[idx];
    if (t < C_CLS) cb[t] = clfb[t];
    __syncthreads();
    int wave = t >> 6, f = t & 63;
    int i = blockIdx.x * 4 + wave;
    double s = (double)score[i];
    double c = exp(-s * s);
    double t2 = 2.0 * s;
    double num = 0.0, den = 0.0;
    #pragma unroll
    for (int k = 0; k < KTERMS; ++k) {
        num += c * Ms[k * 64 + f];
        den += c * m0s[k];
        c *= t2 * (1.0 / (k + 1));     // constant-folded reciprocal
    }
    float z = (float)(num / den);
    zh[wave][f] = h2[(size_t)i * H + f];
    zh[wave][64 + f] = z;
    __syncthreads();
    if (f < C_CLS) {
        float o = cb[f];
        #pragma unroll 8
        for (int u = 0; u < 128; ++u) o += zh[wave][u] * cw[u * C_CLS + f];
        out[(size_t)i * C_CLS + f] = o;
    }
}

// ---------------------------------------------------------------- launch
extern "C" void kernel_launch(void* const* d_in, const int* in_sizes, int n_in,
                              void* d_out, int out_size, void* d_ws, size_t ws_size,
                              hipStream_t stream) {
    (void)in_sizes; (void)n_in; (void)out_size; (void)ws_size;
    const float* x    = (const float*)d_in[0];
    const float* W1   = (const float*)d_in[1];
    const float* b1   = (const float*)d_in[2];
    const float* W2   = (const float*)d_in[3];
    const float* b2   = (const float*)d_in[4];
    const float* aux  = (const float*)d_in[5];
    const float* clfW = (const float*)d_in[6];
    const float* clfb = (const float*)d_in[7];
    const int*   ei   = (const int*)d_in[8];
    float* out = (float*)d_out;
    char* ws = (char*)d_ws;

    float*  hbuf  = (float*)(ws + 0);           // 12000*64*4 = 3,072,000
    float*  h1    = (float*)(ws + 3072000);
    float*  h2    = (float*)(ws + 6144000);
    float*  deg   = (float*)(ws + 9216000);     // 48,000
    float*  invs  = (float*)(ws + 9264000);
    float*  score = (float*)(ws + 9312000);
    int*    ptr   = (int*)  (ws + 9360000);     // 12001 ints
    int*    cur   = (int*)  (ws + 9408016);
    int*    csrc  = (int*)  (ws + 9456016);     // 384000 ints
    double* M     = (double*)(ws + 10992016);   // 24*64 doubles
    double* m0    = (double*)(ws + 11004304);   // 24 doubles

    hipMemsetAsync(cur, 0, N_NODES * sizeof(int), stream);
    hipMemsetAsync(M, 0, (KTERMS * 64 + KTERMS) * sizeof(double), stream);

    init_deg_k<<<47, 256, 0, stream>>>(deg);
    count_k<<<N_EDGES / 256, 256, 0, stream>>>(ei, deg);
    invs_k<<<47, 256, 0, stream>>>(deg, invs);
    scan_k<<<1, 256, 0, stream>>>(deg, ptr);
    fill_k<<<N_EDGES / 256, 256, 0, stream>>>(ei, ptr, cur, csrc);

    gemm1_k<<<N_NODES / 32, 256, 0, stream>>>(x, W1, hbuf);
    agg_k<<<N_NODES, 64, 0, stream>>>(hbuf, b1, deg, invs, ptr, csrc, h1, 1);
    gemm2_k<<<N_NODES / 32, 256, 0, stream>>>(h1, W2, hbuf);
    agg_k<<<N_NODES, 64, 0, stream>>>(hbuf, b2, deg, invs, ptr, csrc, h2, 0);

    score_k<<<N_NODES / 4, 256, 0, stream>>>(h2, aux, score);
    moments_k<<<64, 256, 0, stream>>>(h2, score, M);
    den_k<<<(N_NODES + 63) / 64, 64, 0, stream>>>(score, m0);
    final_k<<<N_NODES / 4, 256, 0, stream>>>(h2, score, M, m0, clfW, clfb, out);
}

// Round 2
// 176.122 us; speedup vs baseline: 1.4068x; 1.4068x over previous
//
#include <hip/hip_runtime.h>
#include <hip/hip_bf16.h>

#define N_NODES 12000
#define N_EDGES 384000
#define F_IN 512
#define H 64
#define C_CLS 7
#define KTERMS 16

// ---------------------------------------------------------------- utilities
__device__ __forceinline__ float wred_f(float x) {
    #pragma unroll
    for (int o = 32; o > 0; o >>= 1) x += __shfl_xor(x, o);
    return x;
}

// ---------------------------------------------------------------- count in-degree (int)
__global__ void count_k(const int* __restrict__ ei, int* __restrict__ degi) {
    int e = blockIdx.x * 256 + threadIdx.x;
    if (e < N_EDGES) atomicAdd(&degi[ei[N_EDGES + e]], 1);
}

// ---------------------------------------------------------------- scan degree -> CSR ptr, also invs = rsqrt(deg+1)
__global__ void scan_k(const int* __restrict__ degi, int* __restrict__ ptr,
                       float* __restrict__ invs) {
    __shared__ int sums[256];
    int t = threadIdx.x;
    const int CH = 48;                 // 256*48 = 12288 >= 12001, degi zero-padded
    int base = t * CH;
    int loc[CH];
    int s = 0;
    #pragma unroll
    for (int q = 0; q < CH / 4; ++q) {
        int4 v = *(const int4*)(degi + base + q * 4);
        loc[q * 4 + 0] = v.x; loc[q * 4 + 1] = v.y;
        loc[q * 4 + 2] = v.z; loc[q * 4 + 3] = v.w;
        s += v.x + v.y + v.z + v.w;
    }
    sums[t] = s;
    __syncthreads();
    for (int o = 1; o < 256; o <<= 1) {
        int v = (t >= o) ? sums[t - o] : 0;
        __syncthreads();
        sums[t] += v;
        __syncthreads();
    }
    int run = sums[t] - s;             // exclusive prefix
    #pragma unroll
    for (int q = 0; q < CH; ++q) {
        int idx = base + q;
        if (idx <= N_NODES) ptr[idx] = run;
        if (idx < N_NODES) invs[idx] = rsqrtf((float)loc[q] + 1.0f);
        run += loc[q];
    }
}

// ---------------------------------------------------------------- fill CSR; precompute edge weight
__global__ void fill_k(const int* __restrict__ ei, const int* __restrict__ ptr,
                       const float* __restrict__ invs, int* __restrict__ cur,
                       int* __restrict__ csrc, float* __restrict__ wedge) {
    int e = blockIdx.x * 256 + threadIdx.x;
    if (e < N_EDGES) {
        int s = ei[e];
        int d = ei[N_EDGES + e];
        int pos = atomicAdd(&cur[d], 1);
        int idx = ptr[d] + pos;
        csrc[idx] = s;
        wedge[idx] = invs[s] * invs[d];
    }
}

// ---------------------------------------------------------------- gemm1: h = x @ W1   [12000x512]@[512x64]
__global__ __launch_bounds__(256) void gemm1_k(const float* __restrict__ x,
                                               const float* __restrict__ W1,
                                               float* __restrict__ outh) {
    __shared__ float xsT[64][34];      // [kk][m], padded
    __shared__ float wsm[64][64];      // [kk][f]
    int t = threadIdx.x;
    int tx = t & 15, ty = t >> 4;
    int i0 = blockIdx.x * 32;
    float acc[2][4] = {};
    for (int k0 = 0; k0 < F_IN; k0 += 64) {
        for (int idx = t; idx < 512; idx += 256) {
            int m = idx >> 4, c4 = idx & 15;
            float4 v = *(const float4*)(x + (size_t)(i0 + m) * F_IN + k0 + c4 * 4);
            xsT[c4 * 4 + 0][m] = v.x;
            xsT[c4 * 4 + 1][m] = v.y;
            xsT[c4 * 4 + 2][m] = v.z;
            xsT[c4 * 4 + 3][m] = v.w;
        }
        for (int idx = t; idx < 1024; idx += 256) {
            int r = idx >> 4, c4 = idx & 15;
            *(float4*)(&wsm[r][c4 * 4]) = *(const float4*)(W1 + (size_t)(k0 + r) * H + c4 * 4);
        }
        __syncthreads();
        #pragma unroll
        for (int kk = 0; kk < 64; ++kk) {
            float2 a = *(const float2*)(&xsT[kk][ty * 2]);
            float4 b = *(const float4*)(&wsm[kk][tx * 4]);
            acc[0][0] += a.x * b.x; acc[0][1] += a.x * b.y;
            acc[0][2] += a.x * b.z; acc[0][3] += a.x * b.w;
            acc[1][0] += a.y * b.x; acc[1][1] += a.y * b.y;
            acc[1][2] += a.y * b.z; acc[1][3] += a.y * b.w;
        }
        __syncthreads();
    }
    #pragma unroll
    for (int q = 0; q < 2; ++q) {
        float4 v = make_float4(acc[q][0], acc[q][1], acc[q][2], acc[q][3]);
        *(float4*)(outh + (size_t)(i0 + ty * 2 + q) * H + tx * 4) = v;
    }
}

// ---------------------------------------------------------------- gemm2: t = h1 @ W2   [12000x64]@[64x64]
__global__ __launch_bounds__(256) void gemm2_k(const float* __restrict__ hin,
                                               const float* __restrict__ W2,
                                               float* __restrict__ outh) {
    __shared__ float ws2[64][64];
    __shared__ float hs[32][64];
    int t = threadIdx.x;
    int i0 = blockIdx.x * 32;
    for (int idx = t; idx < 1024; idx += 256) {
        int r = idx >> 4, c4 = idx & 15;
        *(float4*)(&ws2[r][c4 * 4]) = *(const float4*)(W2 + (size_t)r * H + c4 * 4);
    }
    for (int idx = t; idx < 512; idx += 256) {
        int m = idx >> 4, c4 = idx & 15;
        *(float4*)(&hs[m][c4 * 4]) = *(const float4*)(hin + (size_t)(i0 + m) * H + c4 * 4);
    }
    __syncthreads();
    int f = t & 63, g = t >> 6;
    #pragma unroll
    for (int m = 0; m < 8; ++m) {
        int row = m * 4 + g;
        float acc = 0.f;
        #pragma unroll 16
        for (int k = 0; k < 64; ++k) acc += hs[row][k] * ws2[k][f];
        outh[(size_t)(i0 + row) * H + f] = acc;
    }
}

// ---------------------------------------------------------------- GCN aggregate (CSR gather), 4 nodes/block,
//   edge-unrolled x4; optional relu; optional fused cosine score
__global__ __launch_bounds__(256) void agg_k(const float* __restrict__ hin,
                                             const float* __restrict__ bias,
                                             const float* __restrict__ invs,
                                             const int* __restrict__ ptr,
                                             const int* __restrict__ csrc,
                                             const float* __restrict__ wedge,
                                             float* __restrict__ out,
                                             float* __restrict__ score_out,
                                             const float* __restrict__ aux,
                                             int relu) {
    int t = threadIdx.x;
    int f = t & 63, w = t >> 6;
    int i = blockIdx.x * 4 + w;
    float isq = invs[i];
    float acc = hin[i * H + f] * (isq * isq) + bias[f];  // self-loop: norm = 1/(deg+1)
    int p = ptr[i], p1 = ptr[i + 1];
    for (; p + 4 <= p1; p += 4) {
        int   s0 = csrc[p],     s1 = csrc[p + 1], s2 = csrc[p + 2], s3 = csrc[p + 3];
        float w0 = wedge[p],    w1 = wedge[p + 1], w2 = wedge[p + 2], w3 = wedge[p + 3];
        float v0 = hin[s0 * H + f], v1 = hin[s1 * H + f];
        float v2 = hin[s2 * H + f], v3 = hin[s3 * H + f];
        acc += v0 * w0; acc += v1 * w1; acc += v2 * w2; acc += v3 * w3;
    }
    for (; p < p1; ++p) acc += hin[csrc[p] * H + f] * wedge[p];
    if (relu) acc = fmaxf(acc, 0.f);
    out[i * H + f] = acc;
    if (score_out) {
        float av = aux[f];
        float an2 = wred_f(av * av);
        float an = av / fmaxf(sqrtf(an2), 1e-12f);
        float dp = wred_f(acc * an);
        float nn = wred_f(acc * acc);
        if (f == 0) score_out[i] = dp / fmaxf(sqrtf(nn), 1e-8f);
    }
}

// ---------------------------------------------------------------- fused moments: M[k][f] = sum_j e^{-sj^2} sj^k h2[j][f];
//   m0[k] = same with h == 1.   f32 inner math, f64 atomic accumulate.
#define MBLK 96
__global__ __launch_bounds__(256) void momden_k(const float* __restrict__ h2,
                                                const float* __restrict__ score,
                                                double* __restrict__ M,
                                                double* __restrict__ m0) {
    int t = threadIdx.x;
    int f = t & 63, g = t >> 6;
    float accM[KTERMS], accD[KTERMS];
    #pragma unroll
    for (int k = 0; k < KTERMS; ++k) { accM[k] = 0.f; accD[k] = 0.f; }
    for (int j = blockIdx.x * 4 + g; j < N_NODES; j += MBLK * 4) {
        float sj = score[j];
        float wj = expf(-sj * sj);
        float hv = h2[j * H + f];
        float tm = wj * hv, td = wj;
        #pragma unroll
        for (int k = 0; k < KTERMS; ++k) {
            accM[k] += tm; tm *= sj;
            accD[k] += td; td *= sj;
        }
    }
    __shared__ float Msh[4][KTERMS][64];
    __shared__ float Dsh[4][KTERMS];
    #pragma unroll
    for (int k = 0; k < KTERMS; ++k) Msh[g][k][f] = accM[k];
    if (f == 0) {
        #pragma unroll
        for (int k = 0; k < KTERMS; ++k) Dsh[g][k] = accD[k];
    }
    __syncthreads();
    for (int idx = t; idx < KTERMS * 64; idx += 256) {
        int k = idx >> 6, ff = idx & 63;
        float sum = Msh[0][k][ff] + Msh[1][k][ff] + Msh[2][k][ff] + Msh[3][k][ff];
        unsafeAtomicAdd(&M[idx], (double)sum);
    }
    if (t < KTERMS) {
        float sum = Dsh[0][t] + Dsh[1][t] + Dsh[2][t] + Dsh[3][t];
        unsafeAtomicAdd(&m0[t], (double)sum);
    }
}

// ---------------------------------------------------------------- final: z + concat-classifier (all f32)
__global__ __launch_bounds__(256) void final_k(const float* __restrict__ h2,
                                               const float* __restrict__ score,
                                               const double* __restrict__ M,
                                               const double* __restrict__ m0,
                                               const float* __restrict__ clfW,
                                               const float* __restrict__ clfb,
                                               float* __restrict__ out) {
    __shared__ float Ms[KTERMS * 64];
    __shared__ float m0s[KTERMS];
    __shared__ float cw[128 * C_CLS];
    __shared__ float cb[8];
    __shared__ float zh[4][128];
    int t = threadIdx.x;
    for (int idx = t; idx < KTERMS * 64; idx += 256) Ms[idx] = (float)M[idx];
    if (t < KTERMS) m0s[t] = (float)m0[t];
    for (int idx = t; idx < 128 * C_CLS; idx += 256) cw[idx] = clfW[idx];
    if (t < C_CLS) cb[t] = clfb[t];
    __syncthreads();
    int w = t >> 6, f = t & 63;
    int i = blockIdx.x * 4 + w;
    float s = score[i];
    float c = expf(-s * s);
    float t2 = 2.f * s;
    float num = 0.f, den = 0.f;
    #pragma unroll
    for (int k = 0; k < KTERMS; ++k) {
        num += c * Ms[k * 64 + f];
        den += c * m0s[k];
        c *= t2 * (1.0f / (float)(k + 1));
    }
    float z = num / den;
    zh[w][f] = h2[i * H + f];
    zh[w][64 + f] = z;
    __syncthreads();
    if (f < C_CLS) {
        float o = cb[f];
        #pragma unroll 8
        for (int u = 0; u < 128; ++u) o += zh[w][u] * cw[u * C_CLS + f];
        out[(size_t)i * C_CLS + f] = o;
    }
}

// ---------------------------------------------------------------- launch
extern "C" void kernel_launch(void* const* d_in, const int* in_sizes, int n_in,
                              void* d_out, int out_size, void* d_ws, size_t ws_size,
                              hipStream_t stream) {
    (void)in_sizes; (void)n_in; (void)out_size; (void)ws_size;
    const float* x    = (const float*)d_in[0];
    const float* W1   = (const float*)d_in[1];
    const float* b1   = (const float*)d_in[2];
    const float* W2   = (const float*)d_in[3];
    const float* b2   = (const float*)d_in[4];
    const float* aux  = (const float*)d_in[5];
    const float* clfW = (const float*)d_in[6];
    const float* clfb = (const float*)d_in[7];
    const int*   ei   = (const int*)d_in[8];
    float* out = (float*)d_out;
    char* ws = (char*)d_ws;

    float*  hbuf  = (float*)(ws + 0);            // 12000*64*4
    float*  h1    = (float*)(ws + 3072000);
    float*  h2    = (float*)(ws + 6144000);
    float*  invs  = (float*)(ws + 9216000);      // 48,000
    float*  score = (float*)(ws + 9264000);      // 48,000
    int*    ptr   = (int*)  (ws + 9312000);      // 12001 -> pad 48,016
    int*    csrc  = (int*)  (ws + 9360016);      // 384000*4
    float*  wedge = (float*)(ws + 10896016);     // 384000*4
    // ---- zeroed region (single memset): degi(12288) | cur(12000) | M | m0
    int*    degi  = (int*)  (ws + 12432016);     // 49,152
    int*    cur   = (int*)  (ws + 12481168);     // 48,000
    double* M     = (double*)(ws + 12529168);    // 16*64*8 = 8,192
    double* m0    = (double*)(ws + 12537360);    // 16*8 = 128
    size_t zero_off = 12432016, zero_sz = 49152 + 48000 + 8192 + 128;

    hipMemsetAsync(ws + zero_off, 0, zero_sz, stream);

    count_k<<<N_EDGES / 256, 256, 0, stream>>>(ei, degi);
    scan_k<<<1, 256, 0, stream>>>(degi, ptr, invs);
    fill_k<<<N_EDGES / 256, 256, 0, stream>>>(ei, ptr, invs, cur, csrc, wedge);

    gemm1_k<<<N_NODES / 32, 256, 0, stream>>>(x, W1, hbuf);
    agg_k<<<N_NODES / 4, 256, 0, stream>>>(hbuf, b1, invs, ptr, csrc, wedge,
                                           h1, nullptr, aux, 1);
    gemm2_k<<<N_NODES / 32, 256, 0, stream>>>(h1, W2, hbuf);
    agg_k<<<N_NODES / 4, 256, 0, stream>>>(hbuf, b2, invs, ptr, csrc, wedge,
                                           h2, score, aux, 0);

    momden_k<<<MBLK, 256, 0, stream>>>(h2, score, M, m0);
    final_k<<<N_NODES / 4, 256, 0, stream>>>(h2, score, M, m0, clfW, clfb, out);
}

// Round 3
// 127.739 us; speedup vs baseline: 1.9397x; 1.3788x over previous
//
#include <hip/hip_runtime.h>
#include <hip/hip_bf16.h>

#define N_NODES 12000
#define N_EDGES 384000
#define F_IN 512
#define H 64
#define C_CLS 7
#define KTERMS 16
#define PAD 96
#define MBLK 192

// ---------------------------------------------------------------- utilities
__device__ __forceinline__ float wred_f(float x) {
    #pragma unroll
    for (int o = 32; o > 0; o >>= 1) x += __shfl_xor(x, o);
    return x;
}

// ---------------------------------------------------------------- padded-CSR fill (also produces in-degree in cur)
__global__ void fillpad_k(const int* __restrict__ ei, int* __restrict__ cur,
                          int* __restrict__ csrc) {
    int e = blockIdx.x * 256 + threadIdx.x;
    if (e < N_EDGES) {
        int s = ei[e];
        int d = ei[N_EDGES + e];
        int pos = atomicAdd(&cur[d], 1);
        if (pos < PAD) csrc[d * PAD + pos] = s;   // clamp guard: overflow would fail absmax, not corrupt
    }
}

// ---------------------------------------------------------------- invs = rsqrt(deg+1)
__global__ void invs_k(const int* __restrict__ cur, float* __restrict__ invs) {
    int i = blockIdx.x * 256 + threadIdx.x;
    if (i < N_NODES) invs[i] = rsqrtf((float)cur[i] + 1.0f);
}

// ---------------------------------------------------------------- gemm1: h = x @ W1   [12000x512]@[512x64]
__global__ __launch_bounds__(256) void gemm1_k(const float* __restrict__ x,
                                               const float* __restrict__ W1,
                                               float* __restrict__ outh) {
    __shared__ float xsT[64][34];      // [kk][m], padded
    __shared__ float wsm[64][64];      // [kk][f]
    int t = threadIdx.x;
    int tx = t & 15, ty = t >> 4;
    int i0 = blockIdx.x * 32;
    float acc[2][4] = {};
    for (int k0 = 0; k0 < F_IN; k0 += 64) {
        for (int idx = t; idx < 512; idx += 256) {
            int m = idx >> 4, c4 = idx & 15;
            float4 v = *(const float4*)(x + (size_t)(i0 + m) * F_IN + k0 + c4 * 4);
            xsT[c4 * 4 + 0][m] = v.x;
            xsT[c4 * 4 + 1][m] = v.y;
            xsT[c4 * 4 + 2][m] = v.z;
            xsT[c4 * 4 + 3][m] = v.w;
        }
        for (int idx = t; idx < 1024; idx += 256) {
            int r = idx >> 4, c4 = idx & 15;
            *(float4*)(&wsm[r][c4 * 4]) = *(const float4*)(W1 + (size_t)(k0 + r) * H + c4 * 4);
        }
        __syncthreads();
        #pragma unroll
        for (int kk = 0; kk < 64; ++kk) {
            float2 a = *(const float2*)(&xsT[kk][ty * 2]);
            float4 b = *(const float4*)(&wsm[kk][tx * 4]);
            acc[0][0] += a.x * b.x; acc[0][1] += a.x * b.y;
            acc[0][2] += a.x * b.z; acc[0][3] += a.x * b.w;
            acc[1][0] += a.y * b.x; acc[1][1] += a.y * b.y;
            acc[1][2] += a.y * b.z; acc[1][3] += a.y * b.w;
        }
        __syncthreads();
    }
    #pragma unroll
    for (int q = 0; q < 2; ++q) {
        float4 v = make_float4(acc[q][0], acc[q][1], acc[q][2], acc[q][3]);
        *(float4*)(outh + (size_t)(i0 + ty * 2 + q) * H + tx * 4) = v;
    }
}

// ---------------------------------------------------------------- conv1 aggregate + bias + relu (padded CSR gather)
__global__ __launch_bounds__(256) void agg1_k(const float* __restrict__ hin,
                                              const float* __restrict__ b1,
                                              const float* __restrict__ invs,
                                              const int* __restrict__ cur,
                                              const int* __restrict__ csrc,
                                              float* __restrict__ out) {
    int t = threadIdx.x;
    int f = t & 63, w = t >> 6;
    int i = blockIdx.x * 4 + w;
    float isd = invs[i];
    float acc = hin[i * H + f] * (isd * isd) + b1[f];   // self-loop: 1/(deg+1)
    int deg = min(cur[i], PAD);
    const int* rowp = csrc + i * PAD;
    int p = 0;
    for (; p + 4 <= deg; p += 4) {
        int s0 = rowp[p], s1 = rowp[p + 1], s2 = rowp[p + 2], s3 = rowp[p + 3];
        float w0 = invs[s0] * isd, w1 = invs[s1] * isd;
        float w2 = invs[s2] * isd, w3 = invs[s3] * isd;
        acc += hin[s0 * H + f] * w0 + hin[s1 * H + f] * w1
             + hin[s2 * H + f] * w2 + hin[s3 * H + f] * w3;
    }
    for (; p < deg; ++p) { int s = rowp[p]; acc += hin[s * H + f] * (invs[s] * isd); }
    out[i * H + f] = fmaxf(acc, 0.f);
}

// ---------------------------------------------------------------- conv2: g = A_hat @ h1; h2 = g@W2 + b2 (linearity!)
//   + fused cosine score.  W2 staged in LDS.
__global__ __launch_bounds__(256) void agg2_k(const float* __restrict__ hin,   // h1
                                              const float* __restrict__ W2,
                                              const float* __restrict__ b2,
                                              const float* __restrict__ aux,
                                              const float* __restrict__ invs,
                                              const int* __restrict__ cur,
                                              const int* __restrict__ csrc,
                                              float* __restrict__ h2,
                                              float* __restrict__ score) {
    __shared__ float w2s[64][64];
    __shared__ float gsh[4][64];
    int t = threadIdx.x;
    #pragma unroll
    for (int q = 0; q < 4; ++q) {
        int idx = t + q * 256;         // 0..1023
        int r = idx >> 4, c4 = idx & 15;
        *(float4*)(&w2s[r][c4 * 4]) = *(const float4*)(W2 + r * H + c4 * 4);
    }
    int f = t & 63, w = t >> 6;
    int i = blockIdx.x * 4 + w;
    float isd = invs[i];
    float acc = hin[i * H + f] * (isd * isd);           // no bias inside aggregation
    int deg = min(cur[i], PAD);
    const int* rowp = csrc + i * PAD;
    int p = 0;
    for (; p + 4 <= deg; p += 4) {
        int s0 = rowp[p], s1 = rowp[p + 1], s2 = rowp[p + 2], s3 = rowp[p + 3];
        float w0 = invs[s0] * isd, w1 = invs[s1] * isd;
        float w2_ = invs[s2] * isd, w3 = invs[s3] * isd;
        acc += hin[s0 * H + f] * w0 + hin[s1 * H + f] * w1
             + hin[s2 * H + f] * w2_ + hin[s3 * H + f] * w3;
    }
    for (; p < deg; ++p) { int s = rowp[p]; acc += hin[s * H + f] * (invs[s] * isd); }
    gsh[w][f] = acc;
    __syncthreads();
    float hv = b2[f];
    #pragma unroll 16
    for (int k = 0; k < 64; ++k) hv += gsh[w][k] * w2s[k][f];
    h2[i * H + f] = hv;
    // fused cosine score
    float av = aux[f];
    float an = av * rsqrtf(fmaxf(wred_f(av * av), 1e-24f));
    float dp = wred_f(hv * an);
    float nn = wred_f(hv * hv);
    if (f == 0) score[i] = dp / fmaxf(sqrtf(nn), 1e-8f);
}

// ---------------------------------------------------------------- fused moments: M[k][f] = sum_j w_j s_j^k h2[j][f];
//   m0[k] = sum_j w_j s_j^k.   f32 inner, f64 atomic accumulate.
__global__ __launch_bounds__(256) void momden_k(const float* __restrict__ h2,
                                                const float* __restrict__ score,
                                                double* __restrict__ M,
                                                double* __restrict__ m0) {
    int t = threadIdx.x;
    int f = t & 63, g = t >> 6;
    float accM[KTERMS], accD[KTERMS];
    #pragma unroll
    for (int k = 0; k < KTERMS; ++k) { accM[k] = 0.f; accD[k] = 0.f; }
    for (int j = blockIdx.x * 4 + g; j < N_NODES; j += MBLK * 4) {
        float sj = score[j];
        float wj = expf(-sj * sj);
        float hv = h2[j * H + f];
        float tm = wj * hv, td = wj;
        #pragma unroll
        for (int k = 0; k < KTERMS; ++k) {
            accM[k] += tm; tm *= sj;
            accD[k] += td; td *= sj;
        }
    }
    __shared__ float Msh[4][KTERMS][64];
    __shared__ float Dsh[4][KTERMS];
    #pragma unroll
    for (int k = 0; k < KTERMS; ++k) Msh[g][k][f] = accM[k];
    if (f == 0) {
        #pragma unroll
        for (int k = 0; k < KTERMS; ++k) Dsh[g][k] = accD[k];
    }
    __syncthreads();
    for (int idx = t; idx < KTERMS * 64; idx += 256) {
        int k = idx >> 6, ff = idx & 63;
        float sum = Msh[0][k][ff] + Msh[1][k][ff] + Msh[2][k][ff] + Msh[3][k][ff];
        unsafeAtomicAdd(&M[idx], (double)sum);
    }
    if (t < KTERMS) {
        float sum = Dsh[0][t] + Dsh[1][t] + Dsh[2][t] + Dsh[3][t];
        unsafeAtomicAdd(&m0[t], (double)sum);
    }
}

// ---------------------------------------------------------------- final: z + concat-classifier (all f32)
__global__ __launch_bounds__(256) void final_k(const float* __restrict__ h2,
                                               const float* __restrict__ score,
                                               const double* __restrict__ M,
                                               const double* __restrict__ m0,
                                               const float* __restrict__ clfW,
                                               const float* __restrict__ clfb,
                                               float* __restrict__ out) {
    __shared__ float Ms[KTERMS * 64];
    __shared__ float m0s[KTERMS];
    __shared__ float cw[128 * C_CLS];
    __shared__ float cb[8];
    __shared__ float zh[4][128];
    int t = threadIdx.x;
    for (int idx = t; idx < KTERMS * 64; idx += 256) Ms[idx] = (float)M[idx];
    if (t < KTERMS) m0s[t] = (float)m0[t];
    for (int idx = t; idx < 128 * C_CLS; idx += 256) cw[idx] = clfW[idx];
    if (t < C_CLS) cb[t] = clfb[t];
    __syncthreads();
    int w = t >> 6, f = t & 63;
    int i = blockIdx.x * 4 + w;
    float s = score[i];
    float c = expf(-s * s);
    float t2 = 2.f * s;
    float num = 0.f, den = 0.f;
    #pragma unroll
    for (int k = 0; k < KTERMS; ++k) {
        num += c * Ms[k * 64 + f];
        den += c * m0s[k];
        c *= t2 * (1.0f / (float)(k + 1));
    }
    float z = num / den;
    zh[w][f] = h2[i * H + f];
    zh[w][64 + f] = z;
    __syncthreads();
    if (f < C_CLS) {
        float o = cb[f];
        #pragma unroll 8
        for (int u = 0; u < 128; ++u) o += zh[w][u] * cw[u * C_CLS + f];
        out[(size_t)i * C_CLS + f] = o;
    }
}

// ---------------------------------------------------------------- launch
extern "C" void kernel_launch(void* const* d_in, const int* in_sizes, int n_in,
                              void* d_out, int out_size, void* d_ws, size_t ws_size,
                              hipStream_t stream) {
    (void)in_sizes; (void)n_in; (void)out_size; (void)ws_size;
    const float* x    = (const float*)d_in[0];
    const float* W1   = (const float*)d_in[1];
    const float* b1   = (const float*)d_in[2];
    const float* W2   = (const float*)d_in[3];
    const float* b2   = (const float*)d_in[4];
    const float* aux  = (const float*)d_in[5];
    const float* clfW = (const float*)d_in[6];
    const float* clfb = (const float*)d_in[7];
    const int*   ei   = (const int*)d_in[8];
    float* out = (float*)d_out;
    char* ws = (char*)d_ws;

    float*  hbuf  = (float*)(ws + 0);            // 3,072,000
    float*  h1    = (float*)(ws + 3072000);      // 3,072,000
    float*  h2    = (float*)(ws + 6144000);      // 3,072,000
    float*  invs  = (float*)(ws + 9216000);      // 48,000
    float*  score = (float*)(ws + 9264000);      // 48,000
    int*    csrc  = (int*)  (ws + 9312000);      // 12000*96*4 = 4,608,000
    // ---- zeroed region (single memset): cur | M | m0
    int*    cur   = (int*)  (ws + 13920000);     // 48,000
    double* M     = (double*)(ws + 13968000);    // 8,192
    double* m0    = (double*)(ws + 13976192);    // 128
    const size_t zero_off = 13920000, zero_sz = 48000 + 8192 + 128;

    hipMemsetAsync(ws + zero_off, 0, zero_sz, stream);

    fillpad_k<<<N_EDGES / 256, 256, 0, stream>>>(ei, cur, csrc);
    invs_k<<<47, 256, 0, stream>>>(cur, invs);
    gemm1_k<<<N_NODES / 32, 256, 0, stream>>>(x, W1, hbuf);
    agg1_k<<<N_NODES / 4, 256, 0, stream>>>(hbuf, b1, invs, cur, csrc, h1);
    agg2_k<<<N_NODES / 4, 256, 0, stream>>>(h1, W2, b2, aux, invs, cur, csrc, h2, score);
    momden_k<<<MBLK, 256, 0, stream>>>(h2, score, M, m0);
    final_k<<<N_NODES / 4, 256, 0, stream>>>(h2, score, M, m0, clfW, clfb, out);
}